// Round 1
// baseline (248.923 us; speedup 1.0000x reference)
//
#include <hip/hip_runtime.h>
#include <math.h>

#define NROWS 8192
#define DIM   1024
#define NCHUNK 64   // 8192 / 128 column chunks

typedef __bf16 bf16x8 __attribute__((ext_vector_type(8)));
typedef float  f32x4  __attribute__((ext_vector_type(4)));

// fp32 -> bf16 (RNE), bit-exact, no dependence on hip_bf16 internals
__device__ __forceinline__ unsigned short f2bf(float f) {
    unsigned int u = __float_as_uint(f);
    u = (u + 0x7FFFu + ((u >> 16) & 1u)) >> 16;
    return (unsigned short)u;
}

__device__ __forceinline__ void gld16(const void* g, void* l) {
    __builtin_amdgcn_global_load_lds(
        (__attribute__((address_space(1))) void*)g,
        (__attribute__((address_space(3))) void*)l,
        16, 0, 0);
}

// merge incoming single value v into running top-2 (a1 >= a2)
__device__ __forceinline__ void t2push(float& a1, float& a2, float v) {
    float hi = fmaxf(a1, v);
    float lo = fminf(a1, v);
    a1 = hi;
    a2 = fmaxf(a2, lo);
}

// merge two top-2 pairs: (a1,a2) <- top2 of {a1,a2,b1,b2}
__device__ __forceinline__ void t2merge(float& a1, float& a2, float b1, float b2) {
    float hi = fmaxf(a1, b1);
    float lo = fminf(a1, b1);
    a1 = hi;
    a2 = fmaxf(fmaxf(a2, b2), lo);
}

// ---------------- Kernel A: row L2-normalize, fp32 -> bf16 ----------------
__global__ __launch_bounds__(256) void knorm(const float* __restrict__ x,
                                             unsigned short* __restrict__ xn) {
    const int row = blockIdx.x;
    const int t = threadIdx.x;
    const float4 v = ((const float4*)(x + (size_t)row * DIM))[t];
    float ss = v.x * v.x + v.y * v.y + v.z * v.z + v.w * v.w;
    #pragma unroll
    for (int d = 1; d < 64; d <<= 1) ss += __shfl_xor(ss, d);
    __shared__ float wsum[4];
    if ((t & 63) == 0) wsum[t >> 6] = ss;
    __syncthreads();
    const float tot = wsum[0] + wsum[1] + wsum[2] + wsum[3];
    const float inv = 1.0f / fmaxf(sqrtf(tot), 1e-8f);
    uint2 o;
    o.x = (unsigned)f2bf(v.x * inv) | ((unsigned)f2bf(v.y * inv) << 16);
    o.y = (unsigned)f2bf(v.z * inv) | ((unsigned)f2bf(v.w * inv) << 16);
    *(uint2*)(xn + (size_t)row * DIM + t * 4) = o;
}

// ------- Kernel B: 128x128-tile gram (NT) + fused per-row top-2 over tile -------
// grid (64 cols, 64 rows), 256 threads = 4 waves in 2x2 arrangement
__global__ __launch_bounds__(256) void kgram(const unsigned short* __restrict__ xn,
                                             float2* __restrict__ top2) {
    const int bx = blockIdx.x, by = blockIdx.y;
    const int t = threadIdx.x;
    const int w = t >> 6, lane = t & 63;
    const int wr = w >> 1, wc = w & 1;
    const int g = lane >> 4, c = lane & 15;

    __shared__ __align__(16) unsigned short As[128 * 32];
    __shared__ __align__(16) unsigned short Bs[128 * 32];
    __shared__ float st2[2][128][2];

    f32x4 acc[4][4];
    #pragma unroll
    for (int m = 0; m < 4; m++)
        #pragma unroll
        for (int n = 0; n < 4; n++) acc[m][n] = (f32x4)0.0f;

    // staging addressing: issue i in {0,1}, idx = i*256 + t
    // row = idx>>2 (0..127), k-pack = (idx&3)*8
    const int rA0 = t >> 2, cp0 = (t & 3) * 8;
    const int rA1 = 64 + (t >> 2);
    const unsigned short* gA0 = xn + (size_t)(by * 128 + rA0) * DIM + cp0;
    const unsigned short* gA1 = xn + (size_t)(by * 128 + rA1) * DIM + cp0;
    const unsigned short* gB0 = xn + (size_t)(bx * 128 + rA0) * DIM + cp0;
    const unsigned short* gB1 = xn + (size_t)(bx * 128 + rA1) * DIM + cp0;
    char* lA0 = (char*)As + (size_t)w * 1024;
    char* lA1 = (char*)As + 4096 + (size_t)w * 1024;
    char* lB0 = (char*)Bs + (size_t)w * 1024;
    char* lB1 = (char*)Bs + 4096 + (size_t)w * 1024;

    for (int kk = 0; kk < DIM; kk += 32) {
        __syncthreads();          // previous compute done before overwrite
        gld16(gA0 + kk, lA0);
        gld16(gA1 + kk, lA1);
        gld16(gB0 + kk, lB0);
        gld16(gB1 + kk, lB1);
        __syncthreads();          // staging complete (vmcnt(0) before barrier)

        bf16x8 af[4], bf[4];
        #pragma unroll
        for (int m = 0; m < 4; m++)
            af[m] = *(const bf16x8*)(As + (wr * 64 + m * 16 + c) * 32 + g * 8);
        #pragma unroll
        for (int n = 0; n < 4; n++)
            bf[n] = *(const bf16x8*)(Bs + (wc * 64 + n * 16 + c) * 32 + g * 8);
        #pragma unroll
        for (int m = 0; m < 4; m++)
            #pragma unroll
            for (int n = 0; n < 4; n++)
                acc[m][n] = __builtin_amdgcn_mfma_f32_16x16x32_bf16(af[m], bf[n], acc[m][n], 0, 0, 0);
    }

    // ---- fused top-2 over this tile's 128 columns, per row ----
    // C layout: col = lane&15 (=c), row = (lane>>4)*4 + reg  (within 16x16 frag)
    const bool diagTile = (bx == by);
    #pragma unroll
    for (int m = 0; m < 4; m++) {
        #pragma unroll
        for (int r = 0; r < 4; r++) {
            const int lrow = wr * 64 + m * 16 + g * 4 + r;
            float a1 = -1e30f, a2 = -1e30f;
            #pragma unroll
            for (int n = 0; n < 4; n++) {
                float v = acc[m][n][r];
                if (diagTile && (wc * 64 + n * 16 + c) == lrow) v = -2.0f; // mask diagonal
                t2push(a1, a2, v);
            }
            // butterfly top-2 merge over the 16-lane column group
            #pragma unroll
            for (int d = 1; d < 16; d <<= 1) {
                float b1 = __shfl_xor(a1, d);
                float b2 = __shfl_xor(a2, d);
                t2merge(a1, a2, b1, b2);
            }
            if (c == 0) { st2[wc][lrow][0] = a1; st2[wc][lrow][1] = a2; }
        }
    }
    __syncthreads();
    if (t < 128) {
        float a1 = st2[0][t][0], a2 = st2[0][t][1];
        t2merge(a1, a2, st2[1][t][0], st2[1][t][1]);
        top2[(size_t)(by * 128 + t) * NCHUNK + bx] = make_float2(a1, a2);
    }
}

// ------- Kernel C: merge chunks per row, compute loss/gate, partial sums -------
__global__ __launch_bounds__(256) void kloss(const float2* __restrict__ top2,
                                             float2* __restrict__ partials) {
    const int r = blockIdx.x * 256 + threadIdx.x;   // 0..8191
    const float2* p = top2 + (size_t)r * NCHUNK;
    float a1 = -1e30f, a2 = -1e30f;
    for (int cidx = 0; cidx < NCHUNK; cidx++) {
        float2 q = p[cidx];
        t2merge(a1, a2, q.x, q.y);
    }
    float slg = 0.0f, sg = 0.0f;
    float vs[2] = {a1, a2};
    #pragma unroll
    for (int i = 0; i < 2; i++) {
        float d = sqrtf(fmaxf(2.0f - 2.0f * vs[i], 0.0f));
        float loss = -logf(d + 1e-8f);
        float gate = 1.0f / (1.0f + expf(-(loss - 0.5f) * 10.0f));
        slg += loss * gate;
        sg += gate;
    }
    #pragma unroll
    for (int d = 1; d < 64; d <<= 1) {
        slg += __shfl_xor(slg, d);
        sg  += __shfl_xor(sg, d);
    }
    __shared__ float2 wsum[4];
    if ((threadIdx.x & 63) == 0) wsum[threadIdx.x >> 6] = make_float2(slg, sg);
    __syncthreads();
    if (threadIdx.x == 0) {
        float a = 0.0f, b = 0.0f;
        #pragma unroll
        for (int i = 0; i < 4; i++) { a += wsum[i].x; b += wsum[i].y; }
        partials[blockIdx.x] = make_float2(a, b);
    }
}

// ---------------- Kernel D: final scalar ----------------
__global__ void kfinal(const float2* __restrict__ partials, float* __restrict__ out) {
    const int t = threadIdx.x;  // 64 threads
    float a = 0.0f, b = 0.0f;
    if (t < 32) { float2 p = partials[t]; a = p.x; b = p.y; }
    #pragma unroll
    for (int d = 1; d < 64; d <<= 1) {
        a += __shfl_xor(a, d);
        b += __shfl_xor(b, d);
    }
    if (t == 0) {
        float wm = a / 16384.0f;
        float gm = a / fmaxf(b, 1.0f);
        out[0] = 0.5f * wm + 0.5f * gm;
    }
}

extern "C" void kernel_launch(void* const* d_in, const int* in_sizes, int n_in,
                              void* d_out, int out_size, void* d_ws, size_t ws_size,
                              hipStream_t stream) {
    const float* x = (const float*)d_in[0];
    unsigned short* xn = (unsigned short*)d_ws;                              // 16 MB
    float2* top2 = (float2*)((char*)d_ws + (size_t)16 * 1024 * 1024);        // 4 MB
    float2* partials = (float2*)((char*)d_ws + (size_t)20 * 1024 * 1024);    // 256 B
    float* out = (float*)d_out;

    knorm<<<NROWS, 256, 0, stream>>>(x, xn);
    dim3 gridB(NCHUNK, NCHUNK);
    kgram<<<gridB, 256, 0, stream>>>(xn, top2);
    kloss<<<32, 256, 0, stream>>>(top2, partials);
    kfinal<<<1, 64, 0, stream>>>(partials, out);
}

// Round 2
// 180.849 us; speedup vs baseline: 1.3764x; 1.3764x over previous
//
#include <hip/hip_runtime.h>
#include <math.h>

#define NROWS 8192
#define DIM   1024
#define NCHUNK 64   // 8192 / 128 column chunks
#define NTRI  2080  // 64*65/2 lower-triangle tiles

typedef __bf16 bf16x8 __attribute__((ext_vector_type(8)));
typedef float  f32x4  __attribute__((ext_vector_type(4)));

// fp32 -> bf16 (RNE)
__device__ __forceinline__ unsigned short f2bf(float f) {
    unsigned int u = __float_as_uint(f);
    u = (u + 0x7FFFu + ((u >> 16) & 1u)) >> 16;
    return (unsigned short)u;
}

__device__ __forceinline__ void gld16(const void* g, void* l) {
    __builtin_amdgcn_global_load_lds(
        (__attribute__((address_space(1))) void*)g,
        (__attribute__((address_space(3))) void*)l,
        16, 0, 0);
}

// merge incoming single value v into running top-2 (a1 >= a2)
__device__ __forceinline__ void t2push(float& a1, float& a2, float v) {
    float hi = fmaxf(a1, v);
    float lo = fminf(a1, v);
    a1 = hi;
    a2 = fmaxf(a2, lo);
}

// merge two top-2 pairs: (a1,a2) <- top2 of {a1,a2,b1,b2}
__device__ __forceinline__ void t2merge(float& a1, float& a2, float b1, float b2) {
    float hi = fmaxf(a1, b1);
    float lo = fminf(a1, b1);
    a1 = hi;
    a2 = fmaxf(fmaxf(a2, b2), lo);
}

// ---------------- Kernel A: row L2-normalize, fp32 -> bf16 ----------------
__global__ __launch_bounds__(256) void knorm(const float* __restrict__ x,
                                             unsigned short* __restrict__ xn) {
    const int row = blockIdx.x;
    const int t = threadIdx.x;
    const float4 v = ((const float4*)(x + (size_t)row * DIM))[t];
    float ss = v.x * v.x + v.y * v.y + v.z * v.z + v.w * v.w;
    #pragma unroll
    for (int d = 1; d < 64; d <<= 1) ss += __shfl_xor(ss, d);
    __shared__ float wsum[4];
    if ((t & 63) == 0) wsum[t >> 6] = ss;
    __syncthreads();
    const float tot = wsum[0] + wsum[1] + wsum[2] + wsum[3];
    const float inv = 1.0f / fmaxf(sqrtf(tot), 1e-8f);
    uint2 o;
    o.x = (unsigned)f2bf(v.x * inv) | ((unsigned)f2bf(v.y * inv) << 16);
    o.y = (unsigned)f2bf(v.z * inv) | ((unsigned)f2bf(v.w * inv) << 16);
    *(uint2*)(xn + (size_t)row * DIM + t * 4) = o;
}

// ------- Kernel B: symmetric 128x128-tile gram (NT), bx<=by only.
// Per-row top-2 (rows of by-block) AND per-col top-2 (rows of bx-block via
// symmetry). grid = 2080 (lower triangle), 256 threads = 4 waves (2x2).
__global__ __launch_bounds__(256) void kgram(const unsigned short* __restrict__ xn,
                                             float2* __restrict__ top2) {
    // linear tri index -> (bx, by), bx <= by
    const int bid = blockIdx.x;
    int by = (int)((sqrtf(8.0f * (float)bid + 1.0f) - 1.0f) * 0.5f);
    while ((by + 1) * (by + 2) / 2 <= bid) by++;
    while (by * (by + 1) / 2 > bid) by--;
    const int bx = bid - by * (by + 1) / 2;

    const int t = threadIdx.x;
    const int w = t >> 6, lane = t & 63;
    const int wr = w >> 1, wc = w & 1;
    const int g = lane >> 4, c = lane & 15;

    __shared__ __align__(16) unsigned short As[128 * 32];
    __shared__ __align__(16) unsigned short Bs[128 * 32];
    __shared__ float st2r[2][128][2];
    __shared__ float st2c[2][128][2];

    f32x4 acc[4][4];
    #pragma unroll
    for (int m = 0; m < 4; m++)
        #pragma unroll
        for (int n = 0; n < 4; n++) acc[m][n] = (f32x4)0.0f;

    const int rA0 = t >> 2, cp0 = (t & 3) * 8;
    const unsigned short* gA0 = xn + (size_t)(by * 128 + rA0) * DIM + cp0;
    const unsigned short* gA1 = gA0 + (size_t)64 * DIM;
    const unsigned short* gB0 = xn + (size_t)(bx * 128 + rA0) * DIM + cp0;
    const unsigned short* gB1 = gB0 + (size_t)64 * DIM;
    char* lA0 = (char*)As + (size_t)w * 1024;
    char* lA1 = (char*)As + 4096 + (size_t)w * 1024;
    char* lB0 = (char*)Bs + (size_t)w * 1024;
    char* lB1 = (char*)Bs + 4096 + (size_t)w * 1024;

    for (int kk = 0; kk < DIM; kk += 32) {
        __syncthreads();
        gld16(gA0 + kk, lA0);
        gld16(gA1 + kk, lA1);
        gld16(gB0 + kk, lB0);
        gld16(gB1 + kk, lB1);
        __syncthreads();

        bf16x8 af[4], bf[4];
        #pragma unroll
        for (int m = 0; m < 4; m++)
            af[m] = *(const bf16x8*)(As + (wr * 64 + m * 16 + c) * 32 + g * 8);
        #pragma unroll
        for (int n = 0; n < 4; n++)
            bf[n] = *(const bf16x8*)(Bs + (wc * 64 + n * 16 + c) * 32 + g * 8);
        #pragma unroll
        for (int m = 0; m < 4; m++)
            #pragma unroll
            for (int n = 0; n < 4; n++)
                acc[m][n] = __builtin_amdgcn_mfma_f32_16x16x32_bf16(af[m], bf[n], acc[m][n], 0, 0, 0);
    }

    const bool diagTile = (bx == by);

    // ---- per-row top-2 (rows of by-block, reduce over tile columns) ----
    // C frag layout: col = c, row = g*4 + reg (within 16x16)
    #pragma unroll
    for (int m = 0; m < 4; m++) {
        #pragma unroll
        for (int r = 0; r < 4; r++) {
            const int lrow = wr * 64 + m * 16 + g * 4 + r;
            float a1 = -1e30f, a2 = -1e30f;
            #pragma unroll
            for (int n = 0; n < 4; n++) {
                float v = acc[m][n][r];
                if (diagTile && (wc * 64 + n * 16 + c) == lrow) v = -2.0f;
                t2push(a1, a2, v);
            }
            #pragma unroll
            for (int d = 1; d < 16; d <<= 1) {
                float b1 = __shfl_xor(a1, d);
                float b2 = __shfl_xor(a2, d);
                t2merge(a1, a2, b1, b2);
            }
            if (c == 0) { st2r[wc][lrow][0] = a1; st2r[wc][lrow][1] = a2; }
        }
    }

    // ---- per-col top-2 (rows of bx-block via symmetry; skip on diagonal) ----
    if (!diagTile) {
        #pragma unroll
        for (int n = 0; n < 4; n++) {
            const int lcol = wc * 64 + n * 16 + c;
            float a1 = -1e30f, a2 = -1e30f;
            #pragma unroll
            for (int m = 0; m < 4; m++)
                #pragma unroll
                for (int r = 0; r < 4; r++)
                    t2push(a1, a2, acc[m][n][r]);
            // reduce across the 4 row-groups g (lane bits 4..5)
            #pragma unroll
            for (int d = 16; d < 64; d <<= 1) {
                float b1 = __shfl_xor(a1, d);
                float b2 = __shfl_xor(a2, d);
                t2merge(a1, a2, b1, b2);
            }
            if (g == 0) { st2c[wr][lcol][0] = a1; st2c[wr][lcol][1] = a2; }
        }
    }

    __syncthreads();
    if (t < 128) {
        float a1 = st2r[0][t][0], a2 = st2r[0][t][1];
        t2merge(a1, a2, st2r[1][t][0], st2r[1][t][1]);
        top2[(size_t)(by * 128 + t) * NCHUNK + bx] = make_float2(a1, a2);
    }
    if (!diagTile && t < 128) {
        float a1 = st2c[0][t][0], a2 = st2c[0][t][1];
        t2merge(a1, a2, st2c[1][t][0], st2c[1][t][1]);
        top2[(size_t)(bx * 128 + t) * NCHUNK + by] = make_float2(a1, a2);
    }
}

// ------- Kernel C: one wave per row; lane <-> chunk; loss/gate; block partials -------
__global__ __launch_bounds__(256) void kloss(const float2* __restrict__ top2,
                                             float2* __restrict__ partials) {
    const int t = threadIdx.x;
    const int w = t >> 6, lane = t & 63;
    const int row = blockIdx.x * 4 + w;   // 2048 blocks x 4 waves
    float2 q = top2[(size_t)row * NCHUNK + lane];
    float a1 = q.x, a2 = q.y;
    #pragma unroll
    for (int d = 1; d < 64; d <<= 1) {
        float b1 = __shfl_xor(a1, d);
        float b2 = __shfl_xor(a2, d);
        t2merge(a1, a2, b1, b2);
    }
    __shared__ float2 wsum[4];
    if (lane == 0) {
        float slg = 0.0f, sg = 0.0f;
        float vs[2] = {a1, a2};
        #pragma unroll
        for (int i = 0; i < 2; i++) {
            float dd = sqrtf(fmaxf(2.0f - 2.0f * vs[i], 0.0f));
            float loss = -logf(dd + 1e-8f);
            float gate = 1.0f / (1.0f + expf(-(loss - 0.5f) * 10.0f));
            slg += loss * gate;
            sg += gate;
        }
        wsum[w] = make_float2(slg, sg);
    }
    __syncthreads();
    if (t == 0) {
        float a = 0.0f, b = 0.0f;
        #pragma unroll
        for (int i = 0; i < 4; i++) { a += wsum[i].x; b += wsum[i].y; }
        partials[blockIdx.x] = make_float2(a, b);
    }
}

// ---------------- Kernel D: final scalar over 2048 partials ----------------
__global__ __launch_bounds__(256) void kfinal(const float2* __restrict__ partials,
                                              float* __restrict__ out) {
    const int t = threadIdx.x;
    float a = 0.0f, b = 0.0f;
    for (int i = t; i < 2048; i += 256) {
        float2 p = partials[i];
        a += p.x; b += p.y;
    }
    #pragma unroll
    for (int d = 1; d < 64; d <<= 1) {
        a += __shfl_xor(a, d);
        b += __shfl_xor(b, d);
    }
    __shared__ float2 ws4[4];
    if ((t & 63) == 0) ws4[t >> 6] = make_float2(a, b);
    __syncthreads();
    if (t == 0) {
        float A = 0.0f, Bb = 0.0f;
        #pragma unroll
        for (int i = 0; i < 4; i++) { A += ws4[i].x; Bb += ws4[i].y; }
        float wm = A / 16384.0f;
        float gm = A / fmaxf(Bb, 1.0f);
        out[0] = 0.5f * wm + 0.5f * gm;
    }
}

extern "C" void kernel_launch(void* const* d_in, const int* in_sizes, int n_in,
                              void* d_out, int out_size, void* d_ws, size_t ws_size,
                              hipStream_t stream) {
    const float* x = (const float*)d_in[0];
    unsigned short* xn = (unsigned short*)d_ws;                              // 16 MB
    float2* top2 = (float2*)((char*)d_ws + (size_t)16 * 1024 * 1024);        // 4 MB
    float2* partials = (float2*)((char*)d_ws + (size_t)20 * 1024 * 1024);    // 16 KB
    float* out = (float*)d_out;

    knorm<<<NROWS, 256, 0, stream>>>(x, xn);
    kgram<<<NTRI, 256, 0, stream>>>(xn, top2);
    kloss<<<2048, 256, 0, stream>>>(top2, partials);
    kfinal<<<1, 256, 0, stream>>>(partials, out);
}

// Round 3
// 176.255 us; speedup vs baseline: 1.4123x; 1.0261x over previous
//
#include <hip/hip_runtime.h>
#include <math.h>

#define NROWS 8192
#define DIM   1024
#define NCHUNK 64   // 8192 / 128 column chunks
#define NTRI  2080  // 64*65/2 lower-triangle tiles

typedef __bf16 bf16x8 __attribute__((ext_vector_type(8)));
typedef float  f32x4  __attribute__((ext_vector_type(4)));

// fp32 -> bf16 (RNE)
__device__ __forceinline__ unsigned short f2bf(float f) {
    unsigned int u = __float_as_uint(f);
    u = (u + 0x7FFFu + ((u >> 16) & 1u)) >> 16;
    return (unsigned short)u;
}

__device__ __forceinline__ void gld16(const void* g, void* l) {
    __builtin_amdgcn_global_load_lds(
        (__attribute__((address_space(1))) void*)g,
        (__attribute__((address_space(3))) void*)l,
        16, 0, 0);
}

// DPP rotate-right by N within each 16-lane row (pure VALU cross-lane)
template<int N>
__device__ __forceinline__ float dppror(float v) {
    return __int_as_float(__builtin_amdgcn_update_dpp(
        0, __float_as_int(v), 0x120 + N, 0xF, 0xF, false));
}

// merge incoming single value v into running top-2 (a1 >= a2)
__device__ __forceinline__ void t2push(float& a1, float& a2, float v) {
    float hi = fmaxf(a1, v);
    float lo = fminf(a1, v);
    a1 = hi;
    a2 = fmaxf(a2, lo);
}

// merge two top-2 pairs: (a1,a2) <- top2 of {a1,a2,b1,b2}
__device__ __forceinline__ void t2merge(float& a1, float& a2, float b1, float b2) {
    float hi = fmaxf(a1, b1);
    float lo = fminf(a1, b1);
    a1 = hi;
    a2 = fmaxf(fmaxf(a2, b2), lo);
}

// ---------------- Kernel A: row L2-normalize, fp32 -> bf16 ----------------
// one wave per row, 64 B loaded per lane (4x float4)
__global__ __launch_bounds__(256) void knorm(const float* __restrict__ x,
                                             unsigned short* __restrict__ xn) {
    const int w = threadIdx.x >> 6, lane = threadIdx.x & 63;
    const int row = blockIdx.x * 4 + w;
    const float4* src = (const float4*)(x + (size_t)row * DIM);
    float4 v[4];
    float ss = 0.0f;
    #pragma unroll
    for (int i = 0; i < 4; i++) {
        v[i] = src[lane + 64 * i];
        ss += v[i].x * v[i].x + v[i].y * v[i].y + v[i].z * v[i].z + v[i].w * v[i].w;
    }
    #pragma unroll
    for (int d = 1; d < 64; d <<= 1) ss += __shfl_xor(ss, d);
    const float inv = 1.0f / fmaxf(sqrtf(ss), 1e-8f);
    unsigned short* dst = xn + (size_t)row * DIM;
    #pragma unroll
    for (int i = 0; i < 4; i++) {
        uint2 o;
        o.x = (unsigned)f2bf(v[i].x * inv) | ((unsigned)f2bf(v[i].y * inv) << 16);
        o.y = (unsigned)f2bf(v[i].z * inv) | ((unsigned)f2bf(v[i].w * inv) << 16);
        *(uint2*)(dst + (size_t)(lane + 64 * i) * 4) = o;
    }
}

// ------- Kernel B: symmetric 128x128-tile gram (NT), bx<=by, 2-phase pipelined.
// Double-buffered LDS; next K-step's global_load_lds issued BEFORE current
// compute so staging latency hides under MFMA. DPP rotation top-2 reduce.
__global__ __launch_bounds__(256) void kgram(const unsigned short* __restrict__ xn,
                                             float2* __restrict__ top2) {
    // XCD-bijective chunk swizzle: 2080 = 8 * 260 (locality only)
    const int bid0 = blockIdx.x;
    const int bid = (bid0 & 7) * (NTRI / 8) + (bid0 >> 3);
    // linear tri index -> (bx, by), bx <= by
    int by = (int)((sqrtf(8.0f * (float)bid + 1.0f) - 1.0f) * 0.5f);
    while ((by + 1) * (by + 2) / 2 <= bid) by++;
    while (by * (by + 1) / 2 > bid) by--;
    const int bx = bid - by * (by + 1) / 2;

    const int t = threadIdx.x;
    const int w = t >> 6, lane = t & 63;
    const int wr = w >> 1, wc = w & 1;
    const int g = lane >> 4, c = lane & 15;

    __shared__ __align__(16) unsigned short As[2][128 * 32];
    __shared__ __align__(16) unsigned short Bs[2][128 * 32];
    __shared__ float st2r[2][128][2];
    __shared__ float st2c[2][128][2];

    f32x4 acc[4][4];
    #pragma unroll
    for (int m = 0; m < 4; m++)
        #pragma unroll
        for (int n = 0; n < 4; n++) acc[m][n] = (f32x4)0.0f;

    const int rA0 = t >> 2, cp0 = (t & 3) * 8;
    const unsigned short* gA0 = xn + (size_t)(by * 128 + rA0) * DIM + cp0;
    const unsigned short* gA1 = gA0 + (size_t)64 * DIM;
    const unsigned short* gB0 = xn + (size_t)(bx * 128 + rA0) * DIM + cp0;
    const unsigned short* gB1 = gB0 + (size_t)64 * DIM;

    auto STAGE = [&](int buf, int kk) {
        gld16(gA0 + kk, (char*)&As[buf][0] + (size_t)w * 1024);
        gld16(gA1 + kk, (char*)&As[buf][0] + 4096 + (size_t)w * 1024);
        gld16(gB0 + kk, (char*)&Bs[buf][0] + (size_t)w * 1024);
        gld16(gB1 + kk, (char*)&Bs[buf][0] + 4096 + (size_t)w * 1024);
    };

    // prologue: stage K-step 0 into buffer 0
    STAGE(0, 0);
    __syncthreads();   // implicit vmcnt(0): buf0 ready

    int cur = 0;
    #pragma unroll 2
    for (int kk = 0; kk < DIM; kk += 32) {
        if (kk + 32 < DIM) STAGE(cur ^ 1, kk + 32);   // prefetch next step

        bf16x8 af[4], bf[4];
        #pragma unroll
        for (int m = 0; m < 4; m++)
            af[m] = *(const bf16x8*)(&As[cur][0] + (wr * 64 + m * 16 + c) * 32 + g * 8);
        #pragma unroll
        for (int n = 0; n < 4; n++)
            bf[n] = *(const bf16x8*)(&Bs[cur][0] + (wc * 64 + n * 16 + c) * 32 + g * 8);
        #pragma unroll
        for (int m = 0; m < 4; m++)
            #pragma unroll
            for (int n = 0; n < 4; n++)
                acc[m][n] = __builtin_amdgcn_mfma_f32_16x16x32_bf16(af[m], bf[n], acc[m][n], 0, 0, 0);

        __syncthreads();   // drains vmcnt(0): next buffer staged, old reads done
        cur ^= 1;
    }

    const bool diagTile = (bx == by);

    // ---- per-row top-2 (rows of by-block, reduce over tile columns) ----
    // C frag layout: col = c, row = g*4 + reg (within 16x16)
    #pragma unroll
    for (int m = 0; m < 4; m++) {
        #pragma unroll
        for (int r = 0; r < 4; r++) {
            const int lrow = wr * 64 + m * 16 + g * 4 + r;
            float a1 = -1e30f, a2 = -1e30f;
            #pragma unroll
            for (int n = 0; n < 4; n++) {
                float v = acc[m][n][r];
                if (diagTile && (wc * 64 + n * 16 + c) == lrow) v = -2.0f;
                t2push(a1, a2, v);
            }
            // DPP rotation merge over the 16 column-lanes (disjoint windows: exact)
            { float b1 = dppror<1>(a1), b2 = dppror<1>(a2); t2merge(a1, a2, b1, b2); }
            { float b1 = dppror<2>(a1), b2 = dppror<2>(a2); t2merge(a1, a2, b1, b2); }
            { float b1 = dppror<4>(a1), b2 = dppror<4>(a2); t2merge(a1, a2, b1, b2); }
            { float b1 = dppror<8>(a1), b2 = dppror<8>(a2); t2merge(a1, a2, b1, b2); }
            if (c == 0) { st2r[wc][lrow][0] = a1; st2r[wc][lrow][1] = a2; }
        }
    }

    // ---- per-col top-2 (rows of bx-block via symmetry; skip on diagonal) ----
    if (!diagTile) {
        #pragma unroll
        for (int n = 0; n < 4; n++) {
            const int lcol = wc * 64 + n * 16 + c;
            float a1 = -1e30f, a2 = -1e30f;
            #pragma unroll
            for (int m = 0; m < 4; m++)
                #pragma unroll
                for (int r = 0; r < 4; r++)
                    t2push(a1, a2, acc[m][n][r]);
            // reduce across the 4 row-groups g (lane bits 4..5)
            #pragma unroll
            for (int d = 16; d < 64; d <<= 1) {
                float b1 = __shfl_xor(a1, d);
                float b2 = __shfl_xor(a2, d);
                t2merge(a1, a2, b1, b2);
            }
            if (g == 0) { st2c[wr][lcol][0] = a1; st2c[wr][lcol][1] = a2; }
        }
    }

    __syncthreads();
    if (t < 128) {
        float a1 = st2r[0][t][0], a2 = st2r[0][t][1];
        t2merge(a1, a2, st2r[1][t][0], st2r[1][t][1]);
        top2[(size_t)(by * 128 + t) * NCHUNK + bx] = make_float2(a1, a2);
    }
    if (!diagTile && t < 128) {
        float a1 = st2c[0][t][0], a2 = st2c[0][t][1];
        t2merge(a1, a2, st2c[1][t][0], st2c[1][t][1]);
        top2[(size_t)(bx * 128 + t) * NCHUNK + by] = make_float2(a1, a2);
    }
}

// ------- Kernel C: one wave per row; lane <-> chunk; loss/gate; block partials -------
__global__ __launch_bounds__(256) void kloss(const float2* __restrict__ top2,
                                             float2* __restrict__ partials) {
    const int t = threadIdx.x;
    const int w = t >> 6, lane = t & 63;
    const int row = blockIdx.x * 4 + w;   // 2048 blocks x 4 waves
    float2 q = top2[(size_t)row * NCHUNK + lane];
    float a1 = q.x, a2 = q.y;
    #pragma unroll
    for (int d = 1; d < 64; d <<= 1) {
        float b1 = __shfl_xor(a1, d);
        float b2 = __shfl_xor(a2, d);
        t2merge(a1, a2, b1, b2);
    }
    __shared__ float2 wsum[4];
    if (lane == 0) {
        float slg = 0.0f, sg = 0.0f;
        float vs[2] = {a1, a2};
        #pragma unroll
        for (int i = 0; i < 2; i++) {
            float dd = sqrtf(fmaxf(2.0f - 2.0f * vs[i], 0.0f));
            float loss = -logf(dd + 1e-8f);
            float gate = 1.0f / (1.0f + expf(-(loss - 0.5f) * 10.0f));
            slg += loss * gate;
            sg += gate;
        }
        wsum[w] = make_float2(slg, sg);
    }
    __syncthreads();
    if (t == 0) {
        float a = 0.0f, b = 0.0f;
        #pragma unroll
        for (int i = 0; i < 4; i++) { a += wsum[i].x; b += wsum[i].y; }
        partials[blockIdx.x] = make_float2(a, b);
    }
}

// ---------------- Kernel D: final scalar over 2048 partials ----------------
__global__ __launch_bounds__(256) void kfinal(const float2* __restrict__ partials,
                                              float* __restrict__ out) {
    const int t = threadIdx.x;
    float a = 0.0f, b = 0.0f;
    for (int i = t; i < 2048; i += 256) {
        float2 p = partials[i];
        a += p.x; b += p.y;
    }
    #pragma unroll
    for (int d = 1; d < 64; d <<= 1) {
        a += __shfl_xor(a, d);
        b += __shfl_xor(b, d);
    }
    __shared__ float2 ws4[4];
    if ((t & 63) == 0) ws4[t >> 6] = make_float2(a, b);
    __syncthreads();
    if (t == 0) {
        float A = 0.0f, Bb = 0.0f;
        #pragma unroll
        for (int i = 0; i < 4; i++) { A += ws4[i].x; Bb += ws4[i].y; }
        float wm = A / 16384.0f;
        float gm = A / fmaxf(Bb, 1.0f);
        out[0] = 0.5f * wm + 0.5f * gm;
    }
}

extern "C" void kernel_launch(void* const* d_in, const int* in_sizes, int n_in,
                              void* d_out, int out_size, void* d_ws, size_t ws_size,
                              hipStream_t stream) {
    const float* x = (const float*)d_in[0];
    unsigned short* xn = (unsigned short*)d_ws;                              // 16 MB
    float2* top2 = (float2*)((char*)d_ws + (size_t)16 * 1024 * 1024);        // 4 MB
    float2* partials = (float2*)((char*)d_ws + (size_t)20 * 1024 * 1024);    // 16 KB
    float* out = (float*)d_out;

    knorm<<<NROWS / 4, 256, 0, stream>>>(x, xn);
    kgram<<<NTRI, 256, 0, stream>>>(xn, top2);
    kloss<<<2048, 256, 0, stream>>>(top2, partials);
    kfinal<<<1, 256, 0, stream>>>(partials, out);
}